// Round 8
// baseline (502.872 us; speedup 1.0000x reference)
//
#include <hip/hip_runtime.h>

static constexpr int H = 128, W = 128, HW = H * W;

typedef __attribute__((ext_vector_type(8))) short short8;
typedef __attribute__((ext_vector_type(4))) float f32x4;
typedef unsigned int uint;
typedef unsigned short ushort;

__device__ __forceinline__ float silu_f(float v) { return v / (1.f + __expf(-v)); }
__device__ __forceinline__ ushort f2bf(float f) {
    uint u = __builtin_bit_cast(uint, f);
    return (ushort)((u + 0x7FFFu + ((u >> 16) & 1u)) >> 16);
}
__device__ __forceinline__ float bf2f(ushort s) {
    return __builtin_bit_cast(float, (uint)s << 16);
}

// ================= prep =================
struct PrepArgs {
    const float *w1, *w2, *w3, *wp1, *wp2;
    float *wt1, *wtp1, *polar, *stats;
    ushort *wpk2h, *wpk2l, *wpk3h, *wpk3l, *wpkph, *wpkpl;
    int nstats;
};

__global__ void prep_k(PrepArgs a) {
    int tid = blockIdx.x * 256 + threadIdx.x;
    int stride = gridDim.x * 256;
    for (int i = tid; i < a.nstats; i += stride) a.stats[i] = 0.f;
    for (int i = tid; i < HW; i += stride) {
        int yy = i >> 7, xx = i & 127;
        float X = -1.f + 2.f * xx / 127.f;
        float Y = -1.f + 2.f * yy / 127.f;
        float r = sqrtf(X * X + Y * Y);
        float inv = (r > 0.f) ? 1.f / r : 0.f;
        a.polar[i] = r;
        a.polar[HW + i] = (r > 0.f) ? X * inv : 1.f;
        a.polar[2 * HW + i] = Y * inv;
    }
    for (int i = tid; i < 4 * 9 * 32; i += stride) {
        int cout = i / 36, rem = i % 36;
        a.wt1[rem * 32 + cout] = a.w1[i];
    }
    for (int i = tid; i < 4 * 9 * 16; i += stride) {
        int cout = i / 36, rem = i % 36;
        a.wtp1[rem * 16 + cout] = a.wp1[i];
    }
    for (int i = tid; i < 9 * 2 * 64 * 8; i += stride) {
        int j = i & 7, l = (i >> 3) & 63, t = i >> 9;
        int q = t >> 1, nt = t & 1;
        int k = (l >> 4) * 8 + j;
        int n = nt * 16 + (l & 15);
        int ky = q / 3, kx = q % 3;
        float w = a.w2[((n * 32 + k) * 3 + ky) * 3 + kx];
        ushort h = f2bf(w);
        a.wpk2h[i] = h;
        a.wpk2l[i] = f2bf(w - bf2f(h));
    }
    for (int i = tid; i < 9 * 64 * 8; i += stride) {
        int j = i & 7, l = (i >> 3) & 63, q = i >> 9;
        int k = (l >> 4) * 8 + j;
        int n = l & 15;
        int ky = q / 3, kx = q % 3;
        float w = a.w3[((n * 32 + k) * 3 + ky) * 3 + kx];
        ushort h = f2bf(w);
        a.wpk3h[i] = h;
        a.wpk3l[i] = f2bf(w - bf2f(h));
    }
    for (int i = tid; i < 9 * 64 * 8; i += stride) {
        int j = i & 7, l = (i >> 3) & 63, q = i >> 9;
        int k = (l >> 4) * 8 + j;
        int cin = k & 15;
        int n = l & 15;
        float w = a.wp2[((n * 16 + cin) * 3 + q / 3) * 3 + q % 3];
        ushort h = f2bf(w);
        a.wpkph[i] = h;
        a.wpkpl[i] = f2bf(w - bf2f(h));
    }
}

// ================= conv1 / convp1: fp32 direct =================
template <int COUT, int G>
__global__ __launch_bounds__(256) void conv1_k(
    const float* __restrict__ img, const float* __restrict__ polar,
    const float* __restrict__ wt, const float* __restrict__ bias,
    float* __restrict__ outraw, float* __restrict__ stats) {
    const int tid = threadIdx.x;
    const int y = blockIdx.x * 2 + (tid >> 7);
    const int x = tid & 127;
    const int b = blockIdx.y;

    float acc[COUT];
#pragma unroll
    for (int c = 0; c < COUT; c++) acc[c] = bias[c];

#pragma unroll
    for (int cin = 0; cin < 4; cin++) {
        const float* pl = (cin == 0) ? img + (size_t)b * HW : polar + (size_t)(cin - 1) * HW;
#pragma unroll
        for (int ky = 0; ky < 3; ky++) {
            int yy = y + ky - 1;
            if (yy >= 0 && yy < H) {
                const float* row = pl + yy * W;
                float v1 = row[x];
                float v0 = (x > 0) ? row[x - 1] : 0.f;
                float v2 = (x < 127) ? row[x + 1] : 0.f;
                const float* wr = wt + (cin * 9 + ky * 3) * COUT;
#pragma unroll
                for (int c = 0; c < COUT; c++) {
                    acc[c] = fmaf(wr[c], v0, acc[c]);
                    acc[c] = fmaf(wr[COUT + c], v1, acc[c]);
                    acc[c] = fmaf(wr[2 * COUT + c], v2, acc[c]);
                }
            }
        }
    }

    float4* ob = (float4*)(outraw + ((size_t)b * HW + y * W + x) * COUT);
#pragma unroll
    for (int i = 0; i < COUT / 4; i++)
        ob[i] = make_float4(acc[4 * i], acc[4 * i + 1], acc[4 * i + 2], acc[4 * i + 3]);

    constexpr int CgO = COUT / G;
    __shared__ float sred[4][G][2];
    const int lane = tid & 63, wid = tid >> 6;
#pragma unroll
    for (int g = 0; g < G; g++) {
        float s = 0.f, s2 = 0.f;
#pragma unroll
        for (int c = g * CgO; c < (g + 1) * CgO; c++) { s += acc[c]; s2 += acc[c] * acc[c]; }
#pragma unroll
        for (int off = 32; off > 0; off >>= 1) {
            s += __shfl_down(s, off);
            s2 += __shfl_down(s2, off);
        }
        if (lane == 0) { sred[wid][g][0] = s; sred[wid][g][1] = s2; }
    }
    __syncthreads();
    if (tid < G) {
        float s = 0.f, s2 = 0.f;
#pragma unroll
        for (int w = 0; w < 4; w++) { s += sred[w][tid][0]; s2 += sred[w][tid][1]; }
        atomicAdd(&stats[((size_t)b * G + tid) * 2], s);
        atomicAdd(&stats[((size_t)b * G + tid) * 2 + 1], s2);
    }
}

// ======== rolling-row fused MFMA conv 3x3 (ROWS=16, trunc split, setprio) ========
template <int CIN, int COUT, int Gin, int Gout>
__global__ __launch_bounds__(256, 3) void conv_roll_k(
    const float* __restrict__ raw_in, const float* __restrict__ stats_in,
    const float* __restrict__ gamma, const float* __restrict__ beta,
    const float* __restrict__ bias,
    const short8* __restrict__ wph, const short8* __restrict__ wpl,
    float* __restrict__ outraw, float* __restrict__ stats_out) {

    constexpr int LDSC = 2 * CIN;
    constexpr int SWZM = LDSC / 8 - 1;
    constexpr int NCH8 = CIN / 8;
    constexpr int WN = (COUT == 32) ? 2 : 1;
    constexpr int F = (WN == 2) ? 4 : 2;
    constexpr int ROWS = 16;
    constexpr int ROWB = 128 * LDSC * 2;
    constexpr int CHUNKS = 128 * NCH8 / 256;

    __shared__ __align__(16) ushort ring[3 * 128 * LDSC];
    __shared__ float la[CIN], lc[CIN];

    const int tid = threadIdx.x;
    const int wid = tid >> 6, l = tid & 63;
    const int lm = l & 15, lk = l >> 4;
    const int y0 = blockIdx.x * ROWS;
    const int b = blockIdx.y;
    const int wn = (WN == 2) ? (wid & 1) : 0;
    const int pxb = (WN == 2) ? ((wid >> 1) * 64) : (wid * 32);
    const int ch = wn * 16 + lm;

    if (tid < CIN) {
        constexpr float inv = 1.f / ((CIN / Gin) * (float)HW);
        int g = tid / (CIN / Gin);
        float s = stats_in[((size_t)b * Gin + g) * 2];
        float s2 = stats_in[((size_t)b * Gin + g) * 2 + 1];
        float m = s * inv;
        float rs = rsqrtf(s2 * inv - m * m + 1e-5f);
        float aa = gamma[tid] * rs;
        la[tid] = aa;
        lc[tid] = beta[tid] - m * aa;
    }
    __syncthreads();

    short8 wh[9], wl[9];
#pragma unroll
    for (int q = 0; q < 9; q++) {
        wh[q] = wph[(q * WN + wn) * 64 + l];
        wl[q] = wpl[(q * WN + wn) * 64 + l];
    }
    const float bv = bias[ch];
    const short8 Z8 = {0, 0, 0, 0, 0, 0, 0, 0};
    char* tbw = (char*)ring;

    auto load_row = [&](int ys, float4* g0, float4* g1) {
#pragma unroll
        for (int ck = 0; ck < CHUNKS; ck++) {
            int c = tid + ck * 256;
            int px = c / NCH8, ch8 = c % NCH8;
            const float4* gp = (const float4*)(raw_in + (((size_t)b * HW + ys * W + px) * CIN + ch8 * 8));
            g0[ck] = gp[0];
            g1[ck] = gp[1];
        }
    };
    auto stage_row = [&](int ys, int slot, const float4* g0, const float4* g1) {
#pragma unroll
        for (int ck = 0; ck < CHUNKS; ck++) {
            int c = tid + ck * 256;
            int px = c / NCH8, ch8 = c % NCH8;
            short8 hi8, lo8;
            if (ys >= 0 && ys < H) {
                float vv[8] = {g0[ck].x, g0[ck].y, g0[ck].z, g0[ck].w,
                               g1[ck].x, g1[ck].y, g1[ck].z, g1[ck].w};
#pragma unroll
                for (int e = 0; e < 8; e++) {
                    int cc = ch8 * 8 + e;
                    float f = silu_f(fmaf(vv[e], la[cc], lc[cc]));
                    uint u = __builtin_bit_cast(uint, f);
                    uint uh = u & 0xFFFF0000u;
                    float r = f - __builtin_bit_cast(float, uh);
                    hi8[e] = (short)(u >> 16);
                    lo8[e] = (short)(__builtin_bit_cast(uint, r) >> 16);
                }
            } else {
#pragma unroll
                for (int e = 0; e < 8; e++) { hi8[e] = 0; lo8[e] = 0; }
            }
            int inner = px * LDSC * 2 + ch8 * 16;
            int swz = (px & SWZM) << 4;
            char* sb = tbw + slot * ROWB;
            *(short8*)(sb + (inner ^ swz)) = hi8;
            *(short8*)(sb + ((inner + CIN * 2) ^ swz)) = lo8;
        }
    };

    // prologue: rows y0-1, y0, y0+1
    {
        float4 p0[CHUNKS], p1[CHUNKS];
        for (int pr = 0; pr < 3; pr++) {
            int ys = y0 - 1 + pr;
            if (ys >= 0 && ys < H) load_row(ys, p0, p1);
            stage_row(ys, (ys + 3) % 3, p0, p1);
        }
    }
    __syncthreads();

    float sa = 0.f, sa2 = 0.f;
    float4 g0[CHUNKS], g1[CHUNKS];

    for (int r = 0; r < ROWS; r++) {
        const int y = y0 + r;
        const int ys = y + 2;
        const bool do_stage = (r < ROWS - 1);
        if (do_stage && ys < H) load_row(ys, g0, g1);

        f32x4 acc[F];
#pragma unroll
        for (int f = 0; f < F; f++) acc[f] = (f32x4){0.f, 0.f, 0.f, 0.f};

        const char* sbase[3] = {tbw + ((y + 2) % 3) * ROWB,
                                tbw + ((y + 3) % 3) * ROWB,
                                tbw + ((y + 4) % 3) * ROWB};
        __builtin_amdgcn_s_setprio(1);
#pragma unroll
        for (int q = 0; q < 9; q++) {
            const int ky = q / 3, kx = q % 3;
            const char* sb = sbase[ky];
#pragma unroll
            for (int f = 0; f < F; f++) {
                int xb = pxb + f * 16 + lm + kx - 1;
                bool valid = (xb >= 0) && (xb < 128);
                int xbc = min(max(xb, 0), 127);
                int inner = xbc * LDSC * 2;
                int swz = (xbc & SWZM) << 4;
                if constexpr (CIN == 32) {
                    short8 ah = *(const short8*)(sb + ((inner + lk * 16) ^ swz));
                    short8 al = *(const short8*)(sb + ((inner + (lk + 4) * 16) ^ swz));
                    if (!valid) { ah = Z8; al = Z8; }
                    acc[f] = __builtin_amdgcn_mfma_f32_16x16x32_bf16(ah, wh[q], acc[f], 0, 0, 0);
                    acc[f] = __builtin_amdgcn_mfma_f32_16x16x32_bf16(al, wh[q], acc[f], 0, 0, 0);
                    acc[f] = __builtin_amdgcn_mfma_f32_16x16x32_bf16(ah, wl[q], acc[f], 0, 0, 0);
                } else {
                    short8 a = *(const short8*)(sb + ((inner + lk * 16) ^ swz));
                    if (!valid) a = Z8;
                    acc[f] = __builtin_amdgcn_mfma_f32_16x16x32_bf16(a, wh[q], acc[f], 0, 0, 0);
                    acc[f] = __builtin_amdgcn_mfma_f32_16x16x32_bf16(a, wl[q], acc[f], 0, 0, 0);
                }
            }
        }
        __builtin_amdgcn_s_setprio(0);

#pragma unroll
        for (int f = 0; f < F; f++) {
#pragma unroll
            for (int rr = 0; rr < 4; rr++) {
                int x = pxb + f * 16 + lk * 4 + rr;
                float v = acc[f][rr] + bv;
                outraw[((size_t)b * HW + y * W + x) * COUT + ch] = v;
                sa += v;
                sa2 += v * v;
            }
        }
        __syncthreads();
        if (do_stage) stage_row(ys, (ys + 3) % 3, g0, g1);
        __syncthreads();
    }

    float s = sa, s2 = sa2;
    s += __shfl_xor(s, 16); s2 += __shfl_xor(s2, 16);
    s += __shfl_xor(s, 32); s2 += __shfl_xor(s2, 32);
    constexpr int CgO = COUT / Gout;
#pragma unroll
    for (int m = 1; m < CgO; m <<= 1) { s += __shfl_xor(s, m); s2 += __shfl_xor(s2, m); }
    if (l < 16 && (lm & (CgO - 1)) == 0) {
        int g = ch / CgO;
        atomicAdd(&stats_out[((size_t)b * Gout + g) * 2], s);
        atomicAdd(&stats_out[((size_t)b * Gout + g) * 2 + 1], s2);
    }
}

// ================= fused tail: psik + blur_h + blur_v + grads + warp =================
static __device__ __constant__ float GW0 = 0.40261994689423467f;
static __device__ __constant__ float GW1 = 0.24420134200323348f;
static __device__ __constant__ float GW2 = 0.05448868454964433f;

__global__ __launch_bounds__(512) void tail_k(
    const float* __restrict__ h3, const float* __restrict__ p2,
    const float* __restrict__ img,
    const float* __restrict__ kg3, const float* __restrict__ kbeta3,
    const float* __restrict__ st3,
    const float* __restrict__ pg2, const float* __restrict__ pbeta2,
    const float* __restrict__ stp2,
    const float* __restrict__ kw4, const float* __restrict__ kb4,
    const float* __restrict__ pw3, const float* __restrict__ pb3,
    float* __restrict__ osrc, float* __restrict__ outk,
    float* __restrict__ outpsi, float* __restrict__ oax,
    float* __restrict__ oay) {
    __shared__ float psiA[38 * 128];  // psi, then reused for psi_s
    __shared__ float psiB[38 * 128];  // psi_h

    const int tid = threadIdx.x;
    const int y0 = blockIdx.x * 32;
    const int b = blockIdx.y;

    constexpr float inv = 1.f / (float)(4 * HW);
    float a3[4], c3[4], ap[4], cp[4];
#pragma unroll
    for (int g = 0; g < 4; g++) {
        float s = st3[((size_t)b * 4 + g) * 2];
        float s2 = st3[((size_t)b * 4 + g) * 2 + 1];
        float m = s * inv;
        a3[g] = rsqrtf(s2 * inv - m * m + 1e-5f);
        c3[g] = m;
        s = stp2[((size_t)b * 4 + g) * 2];
        s2 = stp2[((size_t)b * 4 + g) * 2 + 1];
        m = s * inv;
        ap[g] = rsqrtf(s2 * inv - m * m + 1e-5f);
        cp[g] = m;
    }

    // phase A: psi (and k) for 38 rows [y0-3 .. y0+34], reflect rows
    for (int idx = tid; idx < 38 * 128; idx += 512) {
        int s = idx >> 7, j = idx & 127;
        int g = y0 - 3 + s;
        g = (g < 0) ? -g : (g > 127 ? 254 - g : g);
        int rem = g * W + j;

        float hv[16], pv[16];
        const float4* hp = (const float4*)(h3 + ((size_t)b * HW + rem) * 16);
        const float4* pp = (const float4*)(p2 + ((size_t)b * HW + rem) * 16);
#pragma unroll
        for (int t = 0; t < 4; t++) {
            float4 u = hp[t];
            hv[4 * t] = u.x; hv[4 * t + 1] = u.y; hv[4 * t + 2] = u.z; hv[4 * t + 3] = u.w;
            float4 w = pp[t];
            pv[4 * t] = w.x; pv[4 * t + 1] = w.y; pv[4 * t + 2] = w.z; pv[4 * t + 3] = w.w;
        }
        float dk = kb4[0], dp = pb3[0];
#pragma unroll
        for (int c = 0; c < 16; c++) {
            int gg = c >> 2;
            float a = kg3[c] * a3[gg];
            float t = fmaf(hv[c] - c3[gg], a, kbeta3[c]);
            dk = fmaf(kw4[c], silu_f(t), dk);
            a = pg2[c] * ap[gg];
            t = fmaf(pv[c] - cp[gg], a, pbeta2[c]);
            dp = fmaf(pw3[c], silu_f(t), dp);
        }
        float k = 0.5f * (1.f + 0.3f * tanhf(dk));
        float psr = 0.05f * tanhf(dp);
        float X = -1.f + 2.f * j / 127.f;
        float Y = -1.f + 2.f * g / 127.f;
        float r = sqrtf(X * X + Y * Y);
        float psi = fmaf(k, r, psr);
        psiA[idx] = psi;
        if (s >= 3 && s <= 34) {
            int n = (size_t)b * HW + rem;  // g == y0+s-3 here (no reflect)
            outk[n] = k;
            outpsi[n] = psi;
        }
    }
    __syncthreads();

    // phase B: horizontal blur (reflect in x)
    for (int idx = tid; idx < 38 * 128; idx += 512) {
        int s = idx >> 7, j = idx & 127;
        const float* row = psiA + s * 128;
        int jm2 = j - 2; jm2 = jm2 < 0 ? -jm2 : jm2;
        int jm1 = j - 1; jm1 = jm1 < 0 ? -jm1 : jm1;
        int jp1 = j + 1; jp1 = jp1 > 127 ? 254 - jp1 : jp1;
        int jp2 = j + 2; jp2 = jp2 > 127 ? 254 - jp2 : jp2;
        psiB[idx] = GW2 * (row[jm2] + row[jp2]) + GW1 * (row[jm1] + row[jp1]) + GW0 * row[j];
    }
    __syncthreads();

    // phase C: vertical blur -> psiA rows s in [2..35]
    for (int idx = tid; idx < 34 * 128; idx += 512) {
        int s = (idx >> 7) + 2, j = idx & 127;
        psiA[s * 128 + j] = GW2 * (psiB[(s - 2) * 128 + j] + psiB[(s + 2) * 128 + j]) +
                            GW1 * (psiB[(s - 1) * 128 + j] + psiB[(s + 1) * 128 + j]) +
                            GW0 * psiB[s * 128 + j];
    }
    __syncthreads();

    // phase D: grads + soft clamp + warp + blend for owned 32 rows
    const float* im = img + (size_t)b * HW;
    for (int idx = tid; idx < 32 * 128; idx += 512) {
        int r = idx >> 7, j = idx & 127;
        int y = y0 + r, s = r + 3;
        const float* ps = psiA + s * 128;

        float gx;
        if (j == 0)        gx = ps[1] - ps[0];
        else if (j == 127) gx = ps[127] - ps[126];
        else               gx = (ps[j + 1] - ps[j - 1]) * 0.5f;
        gx *= 63.5f;

        float gy;
        if (y == 0)        gy = psiA[(s + 1) * 128 + j] - ps[j];
        else if (y == 127) gy = ps[j] - psiA[(s - 1) * 128 + j];
        else               gy = (psiA[(s + 1) * 128 + j] - psiA[(s - 1) * 128 + j]) * 0.5f;
        gy *= 63.5f;

        float ax = 0.5f * tanhf(gx * 2.f);
        float ay = 0.5f * tanhf(gy * 2.f);

        float X = -1.f + 2.f * j / 127.f;
        float Y = -1.f + 2.f * y / 127.f;
        float bx = fminf(fmaxf(X - ax, -1.f), 1.f);
        float by = fminf(fmaxf(Y - ay, -1.f), 1.f);
        float px = (bx + 1.f) * 0.5f * 127.f;
        float py = (by + 1.f) * 0.5f * 127.f;
        float x0f = floorf(px), y0f = floorf(py);
        float wx = px - x0f, wy = py - y0f;
        int x0i = min(max((int)x0f, 0), 127);
        int x1i = min(x0i + 1, 127);
        int y0i = min(max((int)y0f, 0), 127);
        int y1i = min(y0i + 1, 127);

        float v00 = im[y0i * W + x0i], v01 = im[y0i * W + x1i];
        float v10 = im[y1i * W + x0i], v11 = im[y1i * W + x1i];
        float wrp = v00 * (1.f - wx) * (1.f - wy) + v01 * wx * (1.f - wy) +
                    v10 * (1.f - wx) * wy + v11 * wx * wy;

        int n = (size_t)b * HW + y * W + j;
        osrc[n] = 0.9f * wrp + 0.1f * im[y * W + j];
        oax[n] = ax;
        oay[n] = ay;
    }
}

// ================= launch =================
extern "C" void kernel_launch(void* const* d_in, const int* in_sizes, int n_in,
                              void* d_out, int out_size, void* d_ws, size_t ws_size,
                              hipStream_t stream) {
    const float* img = (const float*)d_in[0];
    const int B = in_sizes[0] / HW;  // 64
    const int npix = B * HW;

    char* base = (char*)d_ws;
    size_t off = 0;
    auto alloc = [&](size_t bytes) {
        char* p = base + off;
        off = (off + bytes + 255) & ~(size_t)255;
        return p;
    };

    float* polar = (float*)alloc(3 * HW * 4);
    float* wt1   = (float*)alloc(4 * 9 * 32 * 4);
    float* wtp1  = (float*)alloc(4 * 9 * 16 * 4);
    ushort* wpk2h = (ushort*)alloc(9 * 2 * 64 * 8 * 2);
    ushort* wpk2l = (ushort*)alloc(9 * 2 * 64 * 8 * 2);
    ushort* wpk3h = (ushort*)alloc(9 * 64 * 8 * 2);
    ushort* wpk3l = (ushort*)alloc(9 * 64 * 8 * 2);
    ushort* wpkph = (ushort*)alloc(9 * 64 * 8 * 2);
    ushort* wpkpl = (ushort*)alloc(9 * 64 * 8 * 2);
    int nstats = B * 56;
    float* stats = (float*)alloc((size_t)nstats * 4);
    float* st1  = stats;                 // B*8*2
    float* st2  = st1 + (size_t)B * 16;  // B*8*2
    float* st3  = st2 + (size_t)B * 16;  // B*4*2
    float* stp1 = st3 + (size_t)B * 8;   // B*4*2
    float* stp2 = stp1 + (size_t)B * 8;  // B*4*2
    size_t head = off;

    int BC = B;
    while (BC > 1) {
        size_t need = head + 2 * ((size_t)BC * HW * 32 * 4 + 256);
        if (need <= ws_size) break;
        BC >>= 1;
    }
    float* R  = (float*)alloc((size_t)BC * HW * 32 * 4);
    float* R2 = (float*)alloc((size_t)BC * HW * 32 * 4);
    float* h3R = R;                          // [BC][HW][16]
    float* p2R = R + (size_t)BC * HW * 16;   // [BC][HW][16]
    float* RpR = R2;                         // convp1 raw

    float* outsrc = (float*)d_out;
    float* outk   = outsrc + (size_t)npix;
    float* outpsi = outk + (size_t)npix;
    float* outax  = outpsi + (size_t)npix;
    float* outay  = outax + (size_t)npix;

    PrepArgs pa;
    pa.w1 = (const float*)d_in[1]; pa.w2 = (const float*)d_in[5];
    pa.w3 = (const float*)d_in[9]; pa.wp1 = (const float*)d_in[15];
    pa.wp2 = (const float*)d_in[19];
    pa.wt1 = wt1; pa.wtp1 = wtp1; pa.polar = polar; pa.stats = stats;
    pa.wpk2h = wpk2h; pa.wpk2l = wpk2l; pa.wpk3h = wpk3h; pa.wpk3l = wpk3l;
    pa.wpkph = wpkph; pa.wpkpl = wpkpl; pa.nstats = nstats;
    prep_k<<<128, 256, 0, stream>>>(pa);

    for (int b0 = 0; b0 < B; b0 += BC) {
        const float* imgc = img + (size_t)b0 * HW;
        dim3 cg1(H / 2, BC), cgr(H / 16, BC);

        // k-tower
        conv1_k<32, 8><<<cg1, 256, 0, stream>>>(imgc, polar, wt1, (const float*)d_in[2],
                                                R, st1 + (size_t)b0 * 16);
        conv_roll_k<32, 32, 8, 8><<<cgr, 256, 0, stream>>>(
            R, st1 + (size_t)b0 * 16, (const float*)d_in[3], (const float*)d_in[4],
            (const float*)d_in[6], (const short8*)wpk2h, (const short8*)wpk2l,
            R2, st2 + (size_t)b0 * 16);
        conv_roll_k<32, 16, 8, 4><<<cgr, 256, 0, stream>>>(
            R2, st2 + (size_t)b0 * 16, (const float*)d_in[7], (const float*)d_in[8],
            (const float*)d_in[10], (const short8*)wpk3h, (const short8*)wpk3l,
            h3R, st3 + (size_t)b0 * 8);

        // p-tower
        conv1_k<16, 4><<<cg1, 256, 0, stream>>>(imgc, polar, wtp1, (const float*)d_in[16],
                                                RpR, stp1 + (size_t)b0 * 8);
        conv_roll_k<16, 16, 4, 4><<<cgr, 256, 0, stream>>>(
            RpR, stp1 + (size_t)b0 * 8, (const float*)d_in[17], (const float*)d_in[18],
            (const float*)d_in[20], (const short8*)wpkph, (const short8*)wpkpl,
            p2R, stp2 + (size_t)b0 * 8);

        // fused tail
        tail_k<<<dim3(4, BC), 512, 0, stream>>>(
            h3R, p2R, imgc,
            (const float*)d_in[11], (const float*)d_in[12], st3 + (size_t)b0 * 8,
            (const float*)d_in[21], (const float*)d_in[22], stp2 + (size_t)b0 * 8,
            (const float*)d_in[13], (const float*)d_in[14],
            (const float*)d_in[23], (const float*)d_in[24],
            outsrc + (size_t)b0 * HW, outk + (size_t)b0 * HW,
            outpsi + (size_t)b0 * HW, outax + (size_t)b0 * HW,
            outay + (size_t)b0 * HW);
    }
}

// Round 9
// 462.082 us; speedup vs baseline: 1.0883x; 1.0883x over previous
//
#include <hip/hip_runtime.h>

static constexpr int H = 128, W = 128, HW = H * W;

typedef __attribute__((ext_vector_type(8))) short short8;
typedef __attribute__((ext_vector_type(4))) float f32x4;
typedef unsigned int uint;
typedef unsigned short ushort;

__device__ __forceinline__ float silu_f(float v) { return v / (1.f + __expf(-v)); }
__device__ __forceinline__ ushort f2bf(float f) {
    uint u = __builtin_bit_cast(uint, f);
    return (ushort)((u + 0x7FFFu + ((u >> 16) & 1u)) >> 16);
}
__device__ __forceinline__ float bf2f(ushort s) {
    return __builtin_bit_cast(float, (uint)s << 16);
}

// ================= prep =================
struct PrepArgs {
    const float *w1, *w2, *w3, *wp1, *wp2;
    float *wt1, *wtp1, *polar, *stats;
    ushort *wpk2h, *wpk2l, *wpk3h, *wpk3l, *wpkph, *wpkpl;
    int nstats;
};

__global__ void prep_k(PrepArgs a) {
    int tid = blockIdx.x * 256 + threadIdx.x;
    int stride = gridDim.x * 256;
    for (int i = tid; i < a.nstats; i += stride) a.stats[i] = 0.f;
    for (int i = tid; i < HW; i += stride) {
        int yy = i >> 7, xx = i & 127;
        float X = -1.f + 2.f * xx / 127.f;
        float Y = -1.f + 2.f * yy / 127.f;
        float r = sqrtf(X * X + Y * Y);
        float inv = (r > 0.f) ? 1.f / r : 0.f;
        a.polar[i] = r;
        a.polar[HW + i] = (r > 0.f) ? X * inv : 1.f;
        a.polar[2 * HW + i] = Y * inv;
    }
    for (int i = tid; i < 4 * 9 * 32; i += stride) {
        int cout = i / 36, rem = i % 36;
        a.wt1[rem * 32 + cout] = a.w1[i];
    }
    for (int i = tid; i < 4 * 9 * 16; i += stride) {
        int cout = i / 36, rem = i % 36;
        a.wtp1[rem * 16 + cout] = a.wp1[i];
    }
    for (int i = tid; i < 9 * 2 * 64 * 8; i += stride) {
        int j = i & 7, l = (i >> 3) & 63, t = i >> 9;
        int q = t >> 1, nt = t & 1;
        int k = (l >> 4) * 8 + j;
        int n = nt * 16 + (l & 15);
        int ky = q / 3, kx = q % 3;
        float w = a.w2[((n * 32 + k) * 3 + ky) * 3 + kx];
        ushort h = f2bf(w);
        a.wpk2h[i] = h;
        a.wpk2l[i] = f2bf(w - bf2f(h));
    }
    for (int i = tid; i < 9 * 64 * 8; i += stride) {
        int j = i & 7, l = (i >> 3) & 63, q = i >> 9;
        int k = (l >> 4) * 8 + j;
        int n = l & 15;
        int ky = q / 3, kx = q % 3;
        float w = a.w3[((n * 32 + k) * 3 + ky) * 3 + kx];
        ushort h = f2bf(w);
        a.wpk3h[i] = h;
        a.wpk3l[i] = f2bf(w - bf2f(h));
    }
    for (int i = tid; i < 9 * 64 * 8; i += stride) {
        int j = i & 7, l = (i >> 3) & 63, q = i >> 9;
        int k = (l >> 4) * 8 + j;
        int cin = k & 15;
        int n = l & 15;
        float w = a.wp2[((n * 16 + cin) * 3 + q / 3) * 3 + q % 3];
        ushort h = f2bf(w);
        a.wpkph[i] = h;
        a.wpkpl[i] = f2bf(w - bf2f(h));
    }
}

// ================= conv1 / convp1: fp32 direct =================
template <int COUT, int G>
__global__ __launch_bounds__(256) void conv1_k(
    const float* __restrict__ img, const float* __restrict__ polar,
    const float* __restrict__ wt, const float* __restrict__ bias,
    float* __restrict__ outraw, float* __restrict__ stats) {
    const int tid = threadIdx.x;
    const int y = blockIdx.x * 2 + (tid >> 7);
    const int x = tid & 127;
    const int b = blockIdx.y;

    float acc[COUT];
#pragma unroll
    for (int c = 0; c < COUT; c++) acc[c] = bias[c];

#pragma unroll
    for (int cin = 0; cin < 4; cin++) {
        const float* pl = (cin == 0) ? img + (size_t)b * HW : polar + (size_t)(cin - 1) * HW;
#pragma unroll
        for (int ky = 0; ky < 3; ky++) {
            int yy = y + ky - 1;
            if (yy >= 0 && yy < H) {
                const float* row = pl + yy * W;
                float v1 = row[x];
                float v0 = (x > 0) ? row[x - 1] : 0.f;
                float v2 = (x < 127) ? row[x + 1] : 0.f;
                const float* wr = wt + (cin * 9 + ky * 3) * COUT;
#pragma unroll
                for (int c = 0; c < COUT; c++) {
                    acc[c] = fmaf(wr[c], v0, acc[c]);
                    acc[c] = fmaf(wr[COUT + c], v1, acc[c]);
                    acc[c] = fmaf(wr[2 * COUT + c], v2, acc[c]);
                }
            }
        }
    }

    float4* ob = (float4*)(outraw + ((size_t)b * HW + y * W + x) * COUT);
#pragma unroll
    for (int i = 0; i < COUT / 4; i++)
        ob[i] = make_float4(acc[4 * i], acc[4 * i + 1], acc[4 * i + 2], acc[4 * i + 3]);

    constexpr int CgO = COUT / G;
    __shared__ float sred[4][G][2];
    const int lane = tid & 63, wid = tid >> 6;
#pragma unroll
    for (int g = 0; g < G; g++) {
        float s = 0.f, s2 = 0.f;
#pragma unroll
        for (int c = g * CgO; c < (g + 1) * CgO; c++) { s += acc[c]; s2 += acc[c] * acc[c]; }
#pragma unroll
        for (int off = 32; off > 0; off >>= 1) {
            s += __shfl_down(s, off);
            s2 += __shfl_down(s2, off);
        }
        if (lane == 0) { sred[wid][g][0] = s; sred[wid][g][1] = s2; }
    }
    __syncthreads();
    if (tid < G) {
        float s = 0.f, s2 = 0.f;
#pragma unroll
        for (int w = 0; w < 4; w++) { s += sred[w][tid][0]; s2 += sred[w][tid][1]; }
        atomicAdd(&stats[((size_t)b * G + tid) * 2], s);
        atomicAdd(&stats[((size_t)b * G + tid) * 2 + 1], s2);
    }
}

// ======== rolling-row fused MFMA conv 3x3 (round-7 config: ROWS=8) ========
template <int CIN, int COUT, int Gin, int Gout>
__global__ __launch_bounds__(256, 3) void conv_roll_k(
    const float* __restrict__ raw_in, const float* __restrict__ stats_in,
    const float* __restrict__ gamma, const float* __restrict__ beta,
    const float* __restrict__ bias,
    const short8* __restrict__ wph, const short8* __restrict__ wpl,
    float* __restrict__ outraw, float* __restrict__ stats_out) {

    constexpr int LDSC = 2 * CIN;
    constexpr int SWZM = LDSC / 8 - 1;
    constexpr int NCH8 = CIN / 8;
    constexpr int WN = (COUT == 32) ? 2 : 1;
    constexpr int F = (WN == 2) ? 4 : 2;
    constexpr int ROWS = 8;
    constexpr int ROWB = 128 * LDSC * 2;
    constexpr int CHUNKS = 128 * NCH8 / 256;

    __shared__ __align__(16) ushort ring[3 * 128 * LDSC];
    __shared__ float la[CIN], lc[CIN];

    const int tid = threadIdx.x;
    const int wid = tid >> 6, l = tid & 63;
    const int lm = l & 15, lk = l >> 4;
    const int y0 = blockIdx.x * ROWS;
    const int b = blockIdx.y;
    const int wn = (WN == 2) ? (wid & 1) : 0;
    const int pxb = (WN == 2) ? ((wid >> 1) * 64) : (wid * 32);
    const int ch = wn * 16 + lm;

    if (tid < CIN) {
        constexpr float inv = 1.f / ((CIN / Gin) * (float)HW);
        int g = tid / (CIN / Gin);
        float s = stats_in[((size_t)b * Gin + g) * 2];
        float s2 = stats_in[((size_t)b * Gin + g) * 2 + 1];
        float m = s * inv;
        float rs = rsqrtf(s2 * inv - m * m + 1e-5f);
        float aa = gamma[tid] * rs;
        la[tid] = aa;
        lc[tid] = beta[tid] - m * aa;
    }
    __syncthreads();

    short8 wh[9], wl[9];
#pragma unroll
    for (int q = 0; q < 9; q++) {
        wh[q] = wph[(q * WN + wn) * 64 + l];
        wl[q] = wpl[(q * WN + wn) * 64 + l];
    }
    const float bv = bias[ch];
    const short8 Z8 = {0, 0, 0, 0, 0, 0, 0, 0};
    char* tbw = (char*)ring;

    auto load_row = [&](int ys, float4* g0, float4* g1) {
#pragma unroll
        for (int ck = 0; ck < CHUNKS; ck++) {
            int c = tid + ck * 256;
            int px = c / NCH8, ch8 = c % NCH8;
            const float4* gp = (const float4*)(raw_in + (((size_t)b * HW + ys * W + px) * CIN + ch8 * 8));
            g0[ck] = gp[0];
            g1[ck] = gp[1];
        }
    };
    auto stage_row = [&](int ys, int slot, const float4* g0, const float4* g1) {
#pragma unroll
        for (int ck = 0; ck < CHUNKS; ck++) {
            int c = tid + ck * 256;
            int px = c / NCH8, ch8 = c % NCH8;
            short8 hi8, lo8;
            if (ys >= 0 && ys < H) {
                float vv[8] = {g0[ck].x, g0[ck].y, g0[ck].z, g0[ck].w,
                               g1[ck].x, g1[ck].y, g1[ck].z, g1[ck].w};
#pragma unroll
                for (int e = 0; e < 8; e++) {
                    int cc = ch8 * 8 + e;
                    float f = silu_f(fmaf(vv[e], la[cc], lc[cc]));
                    ushort hb = f2bf(f);
                    hi8[e] = (short)hb;
                    lo8[e] = (short)f2bf(f - bf2f(hb));
                }
            } else {
#pragma unroll
                for (int e = 0; e < 8; e++) { hi8[e] = 0; lo8[e] = 0; }
            }
            int inner = px * LDSC * 2 + ch8 * 16;
            int swz = (px & SWZM) << 4;
            char* sb = tbw + slot * ROWB;
            *(short8*)(sb + (inner ^ swz)) = hi8;
            *(short8*)(sb + ((inner + CIN * 2) ^ swz)) = lo8;
        }
    };

    // prologue: rows y0-1, y0, y0+1
    {
        float4 p0[CHUNKS], p1[CHUNKS];
        for (int pr = 0; pr < 3; pr++) {
            int ys = y0 - 1 + pr;
            if (ys >= 0 && ys < H) load_row(ys, p0, p1);
            stage_row(ys, (ys + 3) % 3, p0, p1);
        }
    }
    __syncthreads();

    float sa = 0.f, sa2 = 0.f;
    float4 g0[CHUNKS], g1[CHUNKS];

    for (int r = 0; r < ROWS; r++) {
        const int y = y0 + r;
        const int ys = y + 2;
        const bool do_stage = (r < ROWS - 1);
        if (do_stage && ys < H) load_row(ys, g0, g1);  // issue early, consumed after bar

        f32x4 acc[F];
#pragma unroll
        for (int f = 0; f < F; f++) acc[f] = (f32x4){0.f, 0.f, 0.f, 0.f};

        const char* sbase[3] = {tbw + ((y + 2) % 3) * ROWB,
                                tbw + ((y + 3) % 3) * ROWB,
                                tbw + ((y + 4) % 3) * ROWB};
#pragma unroll
        for (int q = 0; q < 9; q++) {
            const int ky = q / 3, kx = q % 3;
            const char* sb = sbase[ky];
#pragma unroll
            for (int f = 0; f < F; f++) {
                int xb = pxb + f * 16 + lm + kx - 1;
                bool valid = (xb >= 0) && (xb < 128);
                int xbc = min(max(xb, 0), 127);
                int inner = xbc * LDSC * 2;
                int swz = (xbc & SWZM) << 4;
                if constexpr (CIN == 32) {
                    short8 ah = *(const short8*)(sb + ((inner + lk * 16) ^ swz));
                    short8 al = *(const short8*)(sb + ((inner + (lk + 4) * 16) ^ swz));
                    if (!valid) { ah = Z8; al = Z8; }
                    acc[f] = __builtin_amdgcn_mfma_f32_16x16x32_bf16(ah, wh[q], acc[f], 0, 0, 0);
                    acc[f] = __builtin_amdgcn_mfma_f32_16x16x32_bf16(al, wh[q], acc[f], 0, 0, 0);
                    acc[f] = __builtin_amdgcn_mfma_f32_16x16x32_bf16(ah, wl[q], acc[f], 0, 0, 0);
                } else {
                    short8 a = *(const short8*)(sb + ((inner + lk * 16) ^ swz));
                    if (!valid) a = Z8;
                    acc[f] = __builtin_amdgcn_mfma_f32_16x16x32_bf16(a, wh[q], acc[f], 0, 0, 0);
                    acc[f] = __builtin_amdgcn_mfma_f32_16x16x32_bf16(a, wl[q], acc[f], 0, 0, 0);
                }
            }
        }

        // store row + stats accumulate
#pragma unroll
        for (int f = 0; f < F; f++) {
#pragma unroll
            for (int rr = 0; rr < 4; rr++) {
                int x = pxb + f * 16 + lk * 4 + rr;
                float v = acc[f][rr] + bv;
                outraw[((size_t)b * HW + y * W + x) * COUT + ch] = v;
                sa += v;
                sa2 += v * v;
            }
        }
        __syncthreads();
        if (do_stage) stage_row(ys, (ys + 3) % 3, g0, g1);
        __syncthreads();
    }

    float s = sa, s2 = sa2;
    s += __shfl_xor(s, 16); s2 += __shfl_xor(s2, 16);
    s += __shfl_xor(s, 32); s2 += __shfl_xor(s2, 32);
    constexpr int CgO = COUT / Gout;
#pragma unroll
    for (int m = 1; m < CgO; m <<= 1) { s += __shfl_xor(s, m); s2 += __shfl_xor(s2, m); }
    if (l < 16 && (lm & (CgO - 1)) == 0) {
        int g = ch / CgO;
        atomicAdd(&stats_out[((size_t)b * Gout + g) * 2], s);
        atomicAdd(&stats_out[((size_t)b * Gout + g) * 2 + 1], s2);
    }
}

// ================= fused tail: psik + blur_h + blur_v + grads + warp =================
static __device__ __constant__ float GW0 = 0.40261994689423467f;
static __device__ __constant__ float GW1 = 0.24420134200323348f;
static __device__ __constant__ float GW2 = 0.05448868454964433f;

__global__ __launch_bounds__(512) void tail_k(
    const float* __restrict__ h3, const float* __restrict__ p2,
    const float* __restrict__ img,
    const float* __restrict__ kg3, const float* __restrict__ kbeta3,
    const float* __restrict__ st3,
    const float* __restrict__ pg2, const float* __restrict__ pbeta2,
    const float* __restrict__ stp2,
    const float* __restrict__ kw4, const float* __restrict__ kb4,
    const float* __restrict__ pw3, const float* __restrict__ pb3,
    float* __restrict__ osrc, float* __restrict__ outk,
    float* __restrict__ outpsi, float* __restrict__ oax,
    float* __restrict__ oay) {
    __shared__ float psiA[38 * 128];  // psi, then reused for psi_s
    __shared__ float psiB[38 * 128];  // psi_h

    const int tid = threadIdx.x;
    const int y0 = blockIdx.x * 32;
    const int b = blockIdx.y;

    constexpr float inv = 1.f / (float)(4 * HW);
    float a3[4], c3[4], ap[4], cp[4];
#pragma unroll
    for (int g = 0; g < 4; g++) {
        float s = st3[((size_t)b * 4 + g) * 2];
        float s2 = st3[((size_t)b * 4 + g) * 2 + 1];
        float m = s * inv;
        a3[g] = rsqrtf(s2 * inv - m * m + 1e-5f);
        c3[g] = m;
        s = stp2[((size_t)b * 4 + g) * 2];
        s2 = stp2[((size_t)b * 4 + g) * 2 + 1];
        m = s * inv;
        ap[g] = rsqrtf(s2 * inv - m * m + 1e-5f);
        cp[g] = m;
    }

    // phase A: psi (and k) for 38 rows [y0-3 .. y0+34], reflect rows
    for (int idx = tid; idx < 38 * 128; idx += 512) {
        int s = idx >> 7, j = idx & 127;
        int g = y0 - 3 + s;
        g = (g < 0) ? -g : (g > 127 ? 254 - g : g);
        int rem = g * W + j;

        float hv[16], pv[16];
        const float4* hp = (const float4*)(h3 + ((size_t)b * HW + rem) * 16);
        const float4* pp = (const float4*)(p2 + ((size_t)b * HW + rem) * 16);
#pragma unroll
        for (int t = 0; t < 4; t++) {
            float4 u = hp[t];
            hv[4 * t] = u.x; hv[4 * t + 1] = u.y; hv[4 * t + 2] = u.z; hv[4 * t + 3] = u.w;
            float4 w = pp[t];
            pv[4 * t] = w.x; pv[4 * t + 1] = w.y; pv[4 * t + 2] = w.z; pv[4 * t + 3] = w.w;
        }
        float dk = kb4[0], dp = pb3[0];
#pragma unroll
        for (int c = 0; c < 16; c++) {
            int gg = c >> 2;
            float a = kg3[c] * a3[gg];
            float t = fmaf(hv[c] - c3[gg], a, kbeta3[c]);
            dk = fmaf(kw4[c], silu_f(t), dk);
            a = pg2[c] * ap[gg];
            t = fmaf(pv[c] - cp[gg], a, pbeta2[c]);
            dp = fmaf(pw3[c], silu_f(t), dp);
        }
        float k = 0.5f * (1.f + 0.3f * tanhf(dk));
        float psr = 0.05f * tanhf(dp);
        float X = -1.f + 2.f * j / 127.f;
        float Y = -1.f + 2.f * g / 127.f;
        float r = sqrtf(X * X + Y * Y);
        float psi = fmaf(k, r, psr);
        psiA[idx] = psi;
        if (s >= 3 && s <= 34) {
            int n = (size_t)b * HW + rem;  // g == y0+s-3 here (no reflect)
            outk[n] = k;
            outpsi[n] = psi;
        }
    }
    __syncthreads();

    // phase B: horizontal blur (reflect in x)
    for (int idx = tid; idx < 38 * 128; idx += 512) {
        int s = idx >> 7, j = idx & 127;
        const float* row = psiA + s * 128;
        int jm2 = j - 2; jm2 = jm2 < 0 ? -jm2 : jm2;
        int jm1 = j - 1; jm1 = jm1 < 0 ? -jm1 : jm1;
        int jp1 = j + 1; jp1 = jp1 > 127 ? 254 - jp1 : jp1;
        int jp2 = j + 2; jp2 = jp2 > 127 ? 254 - jp2 : jp2;
        psiB[idx] = GW2 * (row[jm2] + row[jp2]) + GW1 * (row[jm1] + row[jp1]) + GW0 * row[j];
    }
    __syncthreads();

    // phase C: vertical blur -> psiA rows s in [2..35]
    for (int idx = tid; idx < 34 * 128; idx += 512) {
        int s = (idx >> 7) + 2, j = idx & 127;
        psiA[s * 128 + j] = GW2 * (psiB[(s - 2) * 128 + j] + psiB[(s + 2) * 128 + j]) +
                            GW1 * (psiB[(s - 1) * 128 + j] + psiB[(s + 1) * 128 + j]) +
                            GW0 * psiB[s * 128 + j];
    }
    __syncthreads();

    // phase D: grads + soft clamp + warp + blend for owned 32 rows
    const float* im = img + (size_t)b * HW;
    for (int idx = tid; idx < 32 * 128; idx += 512) {
        int r = idx >> 7, j = idx & 127;
        int y = y0 + r, s = r + 3;
        const float* ps = psiA + s * 128;

        float gx;
        if (j == 0)        gx = ps[1] - ps[0];
        else if (j == 127) gx = ps[127] - ps[126];
        else               gx = (ps[j + 1] - ps[j - 1]) * 0.5f;
        gx *= 63.5f;

        float gy;
        if (y == 0)        gy = psiA[(s + 1) * 128 + j] - ps[j];
        else if (y == 127) gy = ps[j] - psiA[(s - 1) * 128 + j];
        else               gy = (psiA[(s + 1) * 128 + j] - psiA[(s - 1) * 128 + j]) * 0.5f;
        gy *= 63.5f;

        float ax = 0.5f * tanhf(gx * 2.f);
        float ay = 0.5f * tanhf(gy * 2.f);

        float X = -1.f + 2.f * j / 127.f;
        float Y = -1.f + 2.f * y / 127.f;
        float bx = fminf(fmaxf(X - ax, -1.f), 1.f);
        float by = fminf(fmaxf(Y - ay, -1.f), 1.f);
        float px = (bx + 1.f) * 0.5f * 127.f;
        float py = (by + 1.f) * 0.5f * 127.f;
        float x0f = floorf(px), y0f = floorf(py);
        float wx = px - x0f, wy = py - y0f;
        int x0i = min(max((int)x0f, 0), 127);
        int x1i = min(x0i + 1, 127);
        int y0i = min(max((int)y0f, 0), 127);
        int y1i = min(y0i + 1, 127);

        float v00 = im[y0i * W + x0i], v01 = im[y0i * W + x1i];
        float v10 = im[y1i * W + x0i], v11 = im[y1i * W + x1i];
        float wrp = v00 * (1.f - wx) * (1.f - wy) + v01 * wx * (1.f - wy) +
                    v10 * (1.f - wx) * wy + v11 * wx * wy;

        int n = (size_t)b * HW + y * W + j;
        osrc[n] = 0.9f * wrp + 0.1f * im[y * W + j];
        oax[n] = ax;
        oay[n] = ay;
    }
}

// ================= launch =================
extern "C" void kernel_launch(void* const* d_in, const int* in_sizes, int n_in,
                              void* d_out, int out_size, void* d_ws, size_t ws_size,
                              hipStream_t stream) {
    const float* img = (const float*)d_in[0];
    const int B = in_sizes[0] / HW;  // 64
    const int npix = B * HW;

    char* base = (char*)d_ws;
    size_t off = 0;
    auto alloc = [&](size_t bytes) {
        char* p = base + off;
        off = (off + bytes + 255) & ~(size_t)255;
        return p;
    };

    float* polar = (float*)alloc(3 * HW * 4);
    float* wt1   = (float*)alloc(4 * 9 * 32 * 4);
    float* wtp1  = (float*)alloc(4 * 9 * 16 * 4);
    ushort* wpk2h = (ushort*)alloc(9 * 2 * 64 * 8 * 2);
    ushort* wpk2l = (ushort*)alloc(9 * 2 * 64 * 8 * 2);
    ushort* wpk3h = (ushort*)alloc(9 * 64 * 8 * 2);
    ushort* wpk3l = (ushort*)alloc(9 * 64 * 8 * 2);
    ushort* wpkph = (ushort*)alloc(9 * 64 * 8 * 2);
    ushort* wpkpl = (ushort*)alloc(9 * 64 * 8 * 2);
    int nstats = B * 56;
    float* stats = (float*)alloc((size_t)nstats * 4);
    float* st1  = stats;                 // B*8*2
    float* st2  = st1 + (size_t)B * 16;  // B*8*2
    float* st3  = st2 + (size_t)B * 16;  // B*4*2
    float* stp1 = st3 + (size_t)B * 8;   // B*4*2
    float* stp2 = stp1 + (size_t)B * 8;  // B*4*2
    size_t head = off;

    int BC = B;
    while (BC > 1) {
        size_t need = head + 2 * ((size_t)BC * HW * 32 * 4 + 256);
        if (need <= ws_size) break;
        BC >>= 1;
    }
    float* R  = (float*)alloc((size_t)BC * HW * 32 * 4);
    float* R2 = (float*)alloc((size_t)BC * HW * 32 * 4);
    float* h3R = R;                          // [BC][HW][16]
    float* p2R = R + (size_t)BC * HW * 16;   // [BC][HW][16]
    float* RpR = R2;                         // convp1 raw

    float* outsrc = (float*)d_out;
    float* outk   = outsrc + (size_t)npix;
    float* outpsi = outk + (size_t)npix;
    float* outax  = outpsi + (size_t)npix;
    float* outay  = outax + (size_t)npix;

    PrepArgs pa;
    pa.w1 = (const float*)d_in[1]; pa.w2 = (const float*)d_in[5];
    pa.w3 = (const float*)d_in[9]; pa.wp1 = (const float*)d_in[15];
    pa.wp2 = (const float*)d_in[19];
    pa.wt1 = wt1; pa.wtp1 = wtp1; pa.polar = polar; pa.stats = stats;
    pa.wpk2h = wpk2h; pa.wpk2l = wpk2l; pa.wpk3h = wpk3h; pa.wpk3l = wpk3l;
    pa.wpkph = wpkph; pa.wpkpl = wpkpl; pa.nstats = nstats;
    prep_k<<<128, 256, 0, stream>>>(pa);

    for (int b0 = 0; b0 < B; b0 += BC) {
        const float* imgc = img + (size_t)b0 * HW;
        dim3 cg1(H / 2, BC), cgr(H / 8, BC);

        // k-tower
        conv1_k<32, 8><<<cg1, 256, 0, stream>>>(imgc, polar, wt1, (const float*)d_in[2],
                                                R, st1 + (size_t)b0 * 16);
        conv_roll_k<32, 32, 8, 8><<<cgr, 256, 0, stream>>>(
            R, st1 + (size_t)b0 * 16, (const float*)d_in[3], (const float*)d_in[4],
            (const float*)d_in[6], (const short8*)wpk2h, (const short8*)wpk2l,
            R2, st2 + (size_t)b0 * 16);
        conv_roll_k<32, 16, 8, 4><<<cgr, 256, 0, stream>>>(
            R2, st2 + (size_t)b0 * 16, (const float*)d_in[7], (const float*)d_in[8],
            (const float*)d_in[10], (const short8*)wpk3h, (const short8*)wpk3l,
            h3R, st3 + (size_t)b0 * 8);

        // p-tower
        conv1_k<16, 4><<<cg1, 256, 0, stream>>>(imgc, polar, wtp1, (const float*)d_in[16],
                                                RpR, stp1 + (size_t)b0 * 8);
        conv_roll_k<16, 16, 4, 4><<<cgr, 256, 0, stream>>>(
            RpR, stp1 + (size_t)b0 * 8, (const float*)d_in[17], (const float*)d_in[18],
            (const float*)d_in[20], (const short8*)wpkph, (const short8*)wpkpl,
            p2R, stp2 + (size_t)b0 * 8);

        // fused tail
        tail_k<<<dim3(4, BC), 512, 0, stream>>>(
            h3R, p2R, imgc,
            (const float*)d_in[11], (const float*)d_in[12], st3 + (size_t)b0 * 8,
            (const float*)d_in[21], (const float*)d_in[22], stp2 + (size_t)b0 * 8,
            (const float*)d_in[13], (const float*)d_in[14],
            (const float*)d_in[23], (const float*)d_in[24],
            outsrc + (size_t)b0 * HW, outk + (size_t)b0 * HW,
            outpsi + (size_t)b0 * HW, outax + (size_t)b0 * HW,
            outay + (size_t)b0 * HW);
    }
}

// Round 10
// 378.578 us; speedup vs baseline: 1.3283x; 1.2206x over previous
//
#include <hip/hip_runtime.h>

static constexpr int H = 128, W = 128, HW = H * W;

typedef __attribute__((ext_vector_type(8))) short short8;
typedef __attribute__((ext_vector_type(4))) float f32x4;
typedef unsigned int uint;
typedef unsigned short ushort;

__device__ __forceinline__ float rcp_f(float x) { return __builtin_amdgcn_rcpf(x); }
__device__ __forceinline__ float silu_f(float v) { return v * rcp_f(1.f + __expf(-v)); }
__device__ __forceinline__ float tanh_f(float x) { return 1.f - 2.f * rcp_f(__expf(2.f * x) + 1.f); }
__device__ __forceinline__ ushort f2bf(float f) {
    uint u = __builtin_bit_cast(uint, f);
    return (ushort)((u + 0x7FFFu + ((u >> 16) & 1u)) >> 16);
}
__device__ __forceinline__ float bf2f(ushort s) {
    return __builtin_bit_cast(float, (uint)s << 16);
}

// ================= prep =================
struct PrepArgs {
    const float *w1, *w2, *w3, *wp1, *wp2;
    float *wt48, *polar, *stats;
    ushort *wpk2h, *wpk2l, *wpk3h, *wpk3l, *wpkph, *wpkpl;
    int nstats;
};

__global__ void prep_k(PrepArgs a) {
    int tid = blockIdx.x * 256 + threadIdx.x;
    int stride = gridDim.x * 256;
    for (int i = tid; i < a.nstats; i += stride) a.stats[i] = 0.f;
    for (int i = tid; i < HW; i += stride) {
        int yy = i >> 7, xx = i & 127;
        float X = -1.f + 2.f * xx / 127.f;
        float Y = -1.f + 2.f * yy / 127.f;
        float r = sqrtf(X * X + Y * Y);
        float inv = (r > 0.f) ? 1.f / r : 0.f;
        a.polar[i] = r;
        a.polar[HW + i] = (r > 0.f) ? X * inv : 1.f;
        a.polar[2 * HW + i] = Y * inv;
    }
    // merged first-layer weights: wt48[t][c], t = cin*9 + ky*3 + kx, c<32 k-tower, c>=32 p-tower
    for (int i = tid; i < 36 * 48; i += stride) {
        int t = i / 48, c = i % 48;
        int cin = t / 9, k = t % 9;
        float w = (c < 32) ? a.w1[((c * 4 + cin) * 3 + k / 3) * 3 + k % 3]
                           : a.wp1[(((c - 32) * 4 + cin) * 3 + k / 3) * 3 + k % 3];
        a.wt48[i] = w;
    }
    for (int i = tid; i < 9 * 2 * 64 * 8; i += stride) {
        int j = i & 7, l = (i >> 3) & 63, t = i >> 9;
        int q = t >> 1, nt = t & 1;
        int k = (l >> 4) * 8 + j;
        int n = nt * 16 + (l & 15);
        int ky = q / 3, kx = q % 3;
        float w = a.w2[((n * 32 + k) * 3 + ky) * 3 + kx];
        ushort h = f2bf(w);
        a.wpk2h[i] = h;
        a.wpk2l[i] = f2bf(w - bf2f(h));
    }
    for (int i = tid; i < 9 * 64 * 8; i += stride) {
        int j = i & 7, l = (i >> 3) & 63, q = i >> 9;
        int k = (l >> 4) * 8 + j;
        int n = l & 15;
        int ky = q / 3, kx = q % 3;
        float w = a.w3[((n * 32 + k) * 3 + ky) * 3 + kx];
        ushort h = f2bf(w);
        a.wpk3h[i] = h;
        a.wpk3l[i] = f2bf(w - bf2f(h));
    }
    for (int i = tid; i < 9 * 64 * 8; i += stride) {
        int j = i & 7, l = (i >> 3) & 63, q = i >> 9;
        int k = (l >> 4) * 8 + j;
        int cin = k & 15;
        int n = l & 15;
        float w = a.wp2[((n * 16 + cin) * 3 + q / 3) * 3 + q % 3];
        ushort h = f2bf(w);
        a.wpkph[i] = h;
        a.wpkpl[i] = f2bf(w - bf2f(h));
    }
}

// ========== merged first layer: both towers, fp32 direct (K=36, COUT=48) ==========
__global__ __launch_bounds__(256) void conv1f_k(
    const float* __restrict__ img, const float* __restrict__ polar,
    const float* __restrict__ wt48,
    const float* __restrict__ kb1, const float* __restrict__ pb1,
    float* __restrict__ outK, float* __restrict__ outP,
    float* __restrict__ st1, float* __restrict__ stp1) {
    const int tid = threadIdx.x;
    const int y = blockIdx.x * 2 + (tid >> 7);
    const int x = tid & 127;
    const int b = blockIdx.y;

    float acc[48];
#pragma unroll
    for (int c = 0; c < 32; c++) acc[c] = kb1[c];
#pragma unroll
    for (int c = 0; c < 16; c++) acc[32 + c] = pb1[c];

#pragma unroll
    for (int cin = 0; cin < 4; cin++) {
        const float* pl = (cin == 0) ? img + (size_t)b * HW : polar + (size_t)(cin - 1) * HW;
#pragma unroll
        for (int ky = 0; ky < 3; ky++) {
            int yy = y + ky - 1;
            if (yy >= 0 && yy < H) {
                const float* row = pl + yy * W;
                float v1 = row[x];
                float v0 = (x > 0) ? row[x - 1] : 0.f;
                float v2 = (x < 127) ? row[x + 1] : 0.f;
                const float* wr = wt48 + (cin * 9 + ky * 3) * 48;
#pragma unroll
                for (int c = 0; c < 48; c++) {
                    acc[c] = fmaf(wr[c], v0, acc[c]);
                    acc[c] = fmaf(wr[48 + c], v1, acc[c]);
                    acc[c] = fmaf(wr[96 + c], v2, acc[c]);
                }
            }
        }
    }

    float4* obK = (float4*)(outK + ((size_t)b * HW + y * W + x) * 32);
#pragma unroll
    for (int i = 0; i < 8; i++)
        obK[i] = make_float4(acc[4 * i], acc[4 * i + 1], acc[4 * i + 2], acc[4 * i + 3]);
    float4* obP = (float4*)(outP + ((size_t)b * HW + y * W + x) * 16);
#pragma unroll
    for (int i = 0; i < 4; i++)
        obP[i] = make_float4(acc[32 + 4 * i], acc[33 + 4 * i], acc[34 + 4 * i], acc[35 + 4 * i]);

    // stats: 12 uniform groups of 4 channels (8 k-tower + 4 p-tower)
    __shared__ float sred[4][12][2];
    const int lane = tid & 63, wid = tid >> 6;
#pragma unroll
    for (int g = 0; g < 12; g++) {
        float s = 0.f, s2 = 0.f;
#pragma unroll
        for (int c = g * 4; c < g * 4 + 4; c++) { s += acc[c]; s2 += acc[c] * acc[c]; }
#pragma unroll
        for (int off = 32; off > 0; off >>= 1) {
            s += __shfl_down(s, off);
            s2 += __shfl_down(s2, off);
        }
        if (lane == 0) { sred[wid][g][0] = s; sred[wid][g][1] = s2; }
    }
    __syncthreads();
    if (tid < 12) {
        float s = 0.f, s2 = 0.f;
#pragma unroll
        for (int w = 0; w < 4; w++) { s += sred[w][tid][0]; s2 += sred[w][tid][1]; }
        float* dst = (tid < 8) ? &st1[((size_t)b * 8 + tid) * 2]
                               : &stp1[((size_t)b * 4 + (tid - 8)) * 2];
        atomicAdd(dst, s);
        atomicAdd(dst + 1, s2);
    }
}

// ======== rolling-row fused MFMA conv 3x3 (ROWS=8, round-7 measured config) ========
template <int CIN, int COUT, int Gin, int Gout>
__global__ __launch_bounds__(256, 3) void conv_roll_k(
    const float* __restrict__ raw_in, const float* __restrict__ stats_in,
    const float* __restrict__ gamma, const float* __restrict__ beta,
    const float* __restrict__ bias,
    const short8* __restrict__ wph, const short8* __restrict__ wpl,
    float* __restrict__ outraw, float* __restrict__ stats_out) {

    constexpr int LDSC = 2 * CIN;
    constexpr int SWZM = LDSC / 8 - 1;
    constexpr int NCH8 = CIN / 8;
    constexpr int WN = (COUT == 32) ? 2 : 1;
    constexpr int F = (WN == 2) ? 4 : 2;
    constexpr int ROWS = 8;
    constexpr int ROWB = 128 * LDSC * 2;
    constexpr int CHUNKS = 128 * NCH8 / 256;

    __shared__ __align__(16) ushort ring[3 * 128 * LDSC];
    __shared__ float la[CIN], lc[CIN];

    const int tid = threadIdx.x;
    const int wid = tid >> 6, l = tid & 63;
    const int lm = l & 15, lk = l >> 4;
    const int y0 = blockIdx.x * ROWS;
    const int b = blockIdx.y;
    const int wn = (WN == 2) ? (wid & 1) : 0;
    const int pxb = (WN == 2) ? ((wid >> 1) * 64) : (wid * 32);
    const int ch = wn * 16 + lm;

    if (tid < CIN) {
        constexpr float inv = 1.f / ((CIN / Gin) * (float)HW);
        int g = tid / (CIN / Gin);
        float s = stats_in[((size_t)b * Gin + g) * 2];
        float s2 = stats_in[((size_t)b * Gin + g) * 2 + 1];
        float m = s * inv;
        float rs = rsqrtf(s2 * inv - m * m + 1e-5f);
        float aa = gamma[tid] * rs;
        la[tid] = aa;
        lc[tid] = beta[tid] - m * aa;
    }
    __syncthreads();

    short8 wh[9], wl[9];
#pragma unroll
    for (int q = 0; q < 9; q++) {
        wh[q] = wph[(q * WN + wn) * 64 + l];
        wl[q] = wpl[(q * WN + wn) * 64 + l];
    }
    const float bv = bias[ch];
    const short8 Z8 = {0, 0, 0, 0, 0, 0, 0, 0};
    char* tbw = (char*)ring;

    auto load_row = [&](int ys, float4* g0, float4* g1) {
#pragma unroll
        for (int ck = 0; ck < CHUNKS; ck++) {
            int c = tid + ck * 256;
            int px = c / NCH8, ch8 = c % NCH8;
            const float4* gp = (const float4*)(raw_in + (((size_t)b * HW + ys * W + px) * CIN + ch8 * 8));
            g0[ck] = gp[0];
            g1[ck] = gp[1];
        }
    };
    auto stage_row = [&](int ys, int slot, const float4* g0, const float4* g1) {
#pragma unroll
        for (int ck = 0; ck < CHUNKS; ck++) {
            int c = tid + ck * 256;
            int px = c / NCH8, ch8 = c % NCH8;
            short8 hi8, lo8;
            if (ys >= 0 && ys < H) {
                float vv[8] = {g0[ck].x, g0[ck].y, g0[ck].z, g0[ck].w,
                               g1[ck].x, g1[ck].y, g1[ck].z, g1[ck].w};
#pragma unroll
                for (int e = 0; e < 8; e++) {
                    int cc = ch8 * 8 + e;
                    float f = silu_f(fmaf(vv[e], la[cc], lc[cc]));
                    ushort hb = f2bf(f);
                    hi8[e] = (short)hb;
                    lo8[e] = (short)f2bf(f - bf2f(hb));
                }
            } else {
#pragma unroll
                for (int e = 0; e < 8; e++) { hi8[e] = 0; lo8[e] = 0; }
            }
            int inner = px * LDSC * 2 + ch8 * 16;
            int swz = (px & SWZM) << 4;
            char* sb = tbw + slot * ROWB;
            *(short8*)(sb + (inner ^ swz)) = hi8;
            *(short8*)(sb + ((inner + CIN * 2) ^ swz)) = lo8;
        }
    };

    {
        float4 p0[CHUNKS], p1[CHUNKS];
        for (int pr = 0; pr < 3; pr++) {
            int ys = y0 - 1 + pr;
            if (ys >= 0 && ys < H) load_row(ys, p0, p1);
            stage_row(ys, (ys + 3) % 3, p0, p1);
        }
    }
    __syncthreads();

    float sa = 0.f, sa2 = 0.f;
    float4 g0[CHUNKS], g1[CHUNKS];

    for (int r = 0; r < ROWS; r++) {
        const int y = y0 + r;
        const int ys = y + 2;
        const bool do_stage = (r < ROWS - 1);
        if (do_stage && ys < H) load_row(ys, g0, g1);

        f32x4 acc[F];
#pragma unroll
        for (int f = 0; f < F; f++) acc[f] = (f32x4){0.f, 0.f, 0.f, 0.f};

        const char* sbase[3] = {tbw + ((y + 2) % 3) * ROWB,
                                tbw + ((y + 3) % 3) * ROWB,
                                tbw + ((y + 4) % 3) * ROWB};
#pragma unroll
        for (int q = 0; q < 9; q++) {
            const int ky = q / 3, kx = q % 3;
            const char* sb = sbase[ky];
#pragma unroll
            for (int f = 0; f < F; f++) {
                int xb = pxb + f * 16 + lm + kx - 1;
                bool valid = (xb >= 0) && (xb < 128);
                int xbc = min(max(xb, 0), 127);
                int inner = xbc * LDSC * 2;
                int swz = (xbc & SWZM) << 4;
                if constexpr (CIN == 32) {
                    short8 ah = *(const short8*)(sb + ((inner + lk * 16) ^ swz));
                    short8 al = *(const short8*)(sb + ((inner + (lk + 4) * 16) ^ swz));
                    if (!valid) { ah = Z8; al = Z8; }
                    acc[f] = __builtin_amdgcn_mfma_f32_16x16x32_bf16(ah, wh[q], acc[f], 0, 0, 0);
                    acc[f] = __builtin_amdgcn_mfma_f32_16x16x32_bf16(al, wh[q], acc[f], 0, 0, 0);
                    acc[f] = __builtin_amdgcn_mfma_f32_16x16x32_bf16(ah, wl[q], acc[f], 0, 0, 0);
                } else {
                    short8 a = *(const short8*)(sb + ((inner + lk * 16) ^ swz));
                    if (!valid) a = Z8;
                    acc[f] = __builtin_amdgcn_mfma_f32_16x16x32_bf16(a, wh[q], acc[f], 0, 0, 0);
                    acc[f] = __builtin_amdgcn_mfma_f32_16x16x32_bf16(a, wl[q], acc[f], 0, 0, 0);
                }
            }
        }

#pragma unroll
        for (int f = 0; f < F; f++) {
#pragma unroll
            for (int rr = 0; rr < 4; rr++) {
                int x = pxb + f * 16 + lk * 4 + rr;
                float v = acc[f][rr] + bv;
                outraw[((size_t)b * HW + y * W + x) * COUT + ch] = v;
                sa += v;
                sa2 += v * v;
            }
        }
        __syncthreads();
        if (do_stage) stage_row(ys, (ys + 3) % 3, g0, g1);
        __syncthreads();
    }

    float s = sa, s2 = sa2;
    s += __shfl_xor(s, 16); s2 += __shfl_xor(s2, 16);
    s += __shfl_xor(s, 32); s2 += __shfl_xor(s2, 32);
    constexpr int CgO = COUT / Gout;
#pragma unroll
    for (int m = 1; m < CgO; m <<= 1) { s += __shfl_xor(s, m); s2 += __shfl_xor(s2, m); }
    if (l < 16 && (lm & (CgO - 1)) == 0) {
        int g = ch / CgO;
        atomicAdd(&stats_out[((size_t)b * Gout + g) * 2], s);
        atomicAdd(&stats_out[((size_t)b * Gout + g) * 2 + 1], s2);
    }
}

// ================= fused tail (16 owned rows/block) =================
static __device__ __constant__ float GW0 = 0.40261994689423467f;
static __device__ __constant__ float GW1 = 0.24420134200323348f;
static __device__ __constant__ float GW2 = 0.05448868454964433f;

__global__ __launch_bounds__(512) void tail_k(
    const float* __restrict__ h3, const float* __restrict__ p2,
    const float* __restrict__ img,
    const float* __restrict__ kg3, const float* __restrict__ kbeta3,
    const float* __restrict__ st3,
    const float* __restrict__ pg2, const float* __restrict__ pbeta2,
    const float* __restrict__ stp2,
    const float* __restrict__ kw4, const float* __restrict__ kb4,
    const float* __restrict__ pw3, const float* __restrict__ pb3,
    float* __restrict__ osrc, float* __restrict__ outk,
    float* __restrict__ outpsi, float* __restrict__ oax,
    float* __restrict__ oay) {
    __shared__ float psiA[22 * 128];
    __shared__ float psiB[22 * 128];

    const int tid = threadIdx.x;
    const int y0 = blockIdx.x * 16;
    const int b = blockIdx.y;

    constexpr float inv = 1.f / (float)(4 * HW);
    float a3[4], c3[4], ap[4], cp[4];
#pragma unroll
    for (int g = 0; g < 4; g++) {
        float s = st3[((size_t)b * 4 + g) * 2];
        float s2 = st3[((size_t)b * 4 + g) * 2 + 1];
        float m = s * inv;
        a3[g] = rsqrtf(s2 * inv - m * m + 1e-5f);
        c3[g] = m;
        s = stp2[((size_t)b * 4 + g) * 2];
        s2 = stp2[((size_t)b * 4 + g) * 2 + 1];
        m = s * inv;
        ap[g] = rsqrtf(s2 * inv - m * m + 1e-5f);
        cp[g] = m;
    }

    // phase A: psi + k for 22 staged rows [y0-3 .. y0+18], reflect rows
    for (int idx = tid; idx < 22 * 128; idx += 512) {
        int s = idx >> 7, j = idx & 127;
        int g = y0 - 3 + s;
        g = (g < 0) ? -g : (g > 127 ? 254 - g : g);
        int rem = g * W + j;

        float hv[16], pv[16];
        const float4* hp = (const float4*)(h3 + ((size_t)b * HW + rem) * 16);
        const float4* pp = (const float4*)(p2 + ((size_t)b * HW + rem) * 16);
#pragma unroll
        for (int t = 0; t < 4; t++) {
            float4 u = hp[t];
            hv[4 * t] = u.x; hv[4 * t + 1] = u.y; hv[4 * t + 2] = u.z; hv[4 * t + 3] = u.w;
            float4 w = pp[t];
            pv[4 * t] = w.x; pv[4 * t + 1] = w.y; pv[4 * t + 2] = w.z; pv[4 * t + 3] = w.w;
        }
        float dk = kb4[0], dp = pb3[0];
#pragma unroll
        for (int c = 0; c < 16; c++) {
            int gg = c >> 2;
            float a = kg3[c] * a3[gg];
            float t = fmaf(hv[c] - c3[gg], a, kbeta3[c]);
            dk = fmaf(kw4[c], silu_f(t), dk);
            a = pg2[c] * ap[gg];
            t = fmaf(pv[c] - cp[gg], a, pbeta2[c]);
            dp = fmaf(pw3[c], silu_f(t), dp);
        }
        float k = 0.5f * (1.f + 0.3f * tanh_f(dk));
        float psr = 0.05f * tanh_f(dp);
        float X = -1.f + 2.f * j / 127.f;
        float Y = -1.f + 2.f * g / 127.f;
        float r = sqrtf(X * X + Y * Y);
        float psi = fmaf(k, r, psr);
        psiA[idx] = psi;
        if (s >= 3 && s < 19) {
            int n = (size_t)b * HW + rem;
            outk[n] = k;
            outpsi[n] = psi;
        }
    }
    __syncthreads();

    // phase B: horizontal blur
    for (int idx = tid; idx < 22 * 128; idx += 512) {
        int s = idx >> 7, j = idx & 127;
        const float* row = psiA + s * 128;
        int jm2 = j - 2; jm2 = jm2 < 0 ? -jm2 : jm2;
        int jm1 = j - 1; jm1 = jm1 < 0 ? -jm1 : jm1;
        int jp1 = j + 1; jp1 = jp1 > 127 ? 254 - jp1 : jp1;
        int jp2 = j + 2; jp2 = jp2 > 127 ? 254 - jp2 : jp2;
        psiB[idx] = GW2 * (row[jm2] + row[jp2]) + GW1 * (row[jm1] + row[jp1]) + GW0 * row[j];
    }
    __syncthreads();

    // phase C: vertical blur -> psiA rows s in [2..20)
    for (int idx = tid; idx < 18 * 128; idx += 512) {
        int s = (idx >> 7) + 2, j = idx & 127;
        psiA[s * 128 + j] = GW2 * (psiB[(s - 2) * 128 + j] + psiB[(s + 2) * 128 + j]) +
                            GW1 * (psiB[(s - 1) * 128 + j] + psiB[(s + 1) * 128 + j]) +
                            GW0 * psiB[s * 128 + j];
    }
    __syncthreads();

    // phase D: grads + soft clamp + warp + blend for owned 16 rows
    const float* im = img + (size_t)b * HW;
    for (int idx = tid; idx < 16 * 128; idx += 512) {
        int r = idx >> 7, j = idx & 127;
        int y = y0 + r, s = r + 3;
        const float* ps = psiA + s * 128;

        float gx;
        if (j == 0)        gx = ps[1] - ps[0];
        else if (j == 127) gx = ps[127] - ps[126];
        else               gx = (ps[j + 1] - ps[j - 1]) * 0.5f;
        gx *= 63.5f;

        float gy;
        if (y == 0)        gy = psiA[(s + 1) * 128 + j] - ps[j];
        else if (y == 127) gy = ps[j] - psiA[(s - 1) * 128 + j];
        else               gy = (psiA[(s + 1) * 128 + j] - psiA[(s - 1) * 128 + j]) * 0.5f;
        gy *= 63.5f;

        float ax = 0.5f * tanh_f(gx * 2.f);
        float ay = 0.5f * tanh_f(gy * 2.f);

        float X = -1.f + 2.f * j / 127.f;
        float Y = -1.f + 2.f * y / 127.f;
        float bx = fminf(fmaxf(X - ax, -1.f), 1.f);
        float by = fminf(fmaxf(Y - ay, -1.f), 1.f);
        float px = (bx + 1.f) * 0.5f * 127.f;
        float py = (by + 1.f) * 0.5f * 127.f;
        float x0f = floorf(px), y0f = floorf(py);
        float wx = px - x0f, wy = py - y0f;
        int x0i = min(max((int)x0f, 0), 127);
        int x1i = min(x0i + 1, 127);
        int y0i = min(max((int)y0f, 0), 127);
        int y1i = min(y0i + 1, 127);

        float v00 = im[y0i * W + x0i], v01 = im[y0i * W + x1i];
        float v10 = im[y1i * W + x0i], v11 = im[y1i * W + x1i];
        float wrp = v00 * (1.f - wx) * (1.f - wy) + v01 * wx * (1.f - wy) +
                    v10 * (1.f - wx) * wy + v11 * wx * wy;

        int n = (size_t)b * HW + y * W + j;
        osrc[n] = 0.9f * wrp + 0.1f * im[y * W + j];
        oax[n] = ax;
        oay[n] = ay;
    }
}

// ================= launch =================
extern "C" void kernel_launch(void* const* d_in, const int* in_sizes, int n_in,
                              void* d_out, int out_size, void* d_ws, size_t ws_size,
                              hipStream_t stream) {
    const float* img = (const float*)d_in[0];
    const int B = in_sizes[0] / HW;  // 64
    const int npix = B * HW;

    char* base = (char*)d_ws;
    size_t off = 0;
    auto alloc = [&](size_t bytes) {
        char* p = base + off;
        off = (off + bytes + 255) & ~(size_t)255;
        return p;
    };

    float* polar = (float*)alloc(3 * HW * 4);
    float* wt48  = (float*)alloc(36 * 48 * 4);
    ushort* wpk2h = (ushort*)alloc(9 * 2 * 64 * 8 * 2);
    ushort* wpk2l = (ushort*)alloc(9 * 2 * 64 * 8 * 2);
    ushort* wpk3h = (ushort*)alloc(9 * 64 * 8 * 2);
    ushort* wpk3l = (ushort*)alloc(9 * 64 * 8 * 2);
    ushort* wpkph = (ushort*)alloc(9 * 64 * 8 * 2);
    ushort* wpkpl = (ushort*)alloc(9 * 64 * 8 * 2);
    int nstats = B * 56;
    float* stats = (float*)alloc((size_t)nstats * 4);
    float* st1  = stats;                 // B*8*2
    float* st2  = st1 + (size_t)B * 16;  // B*8*2
    float* st3  = st2 + (size_t)B * 16;  // B*4*2
    float* stp1 = st3 + (size_t)B * 8;   // B*4*2
    float* stp2 = stp1 + (size_t)B * 8;  // B*4*2
    size_t head = off;

    // per-chunk footprint: R(32ch) + R2(32ch, first half doubles as Rp) + p2(16ch)
    int BC = B;
    while (BC > 1) {
        size_t need = head + (size_t)BC * HW * 80 * 4 + 3 * 256;
        if (need <= ws_size) break;
        BC >>= 1;
    }
    float* R   = (float*)alloc((size_t)BC * HW * 32 * 4);
    float* R2  = (float*)alloc((size_t)BC * HW * 32 * 4);
    float* p2B = (float*)alloc((size_t)BC * HW * 16 * 4);
    float* RpB = R2;   // p-tower raw (16ch) lives in R2's bytes until conv2 runs
    float* h3B = R;    // conv3 output overwrites R (dead after conv2 reads it)

    float* outsrc = (float*)d_out;
    float* outk   = outsrc + (size_t)npix;
    float* outpsi = outk + (size_t)npix;
    float* outax  = outpsi + (size_t)npix;
    float* outay  = outax + (size_t)npix;

    PrepArgs pa;
    pa.w1 = (const float*)d_in[1]; pa.w2 = (const float*)d_in[5];
    pa.w3 = (const float*)d_in[9]; pa.wp1 = (const float*)d_in[15];
    pa.wp2 = (const float*)d_in[19];
    pa.wt48 = wt48; pa.polar = polar; pa.stats = stats;
    pa.wpk2h = wpk2h; pa.wpk2l = wpk2l; pa.wpk3h = wpk3h; pa.wpk3l = wpk3l;
    pa.wpkph = wpkph; pa.wpkpl = wpkpl; pa.nstats = nstats;
    prep_k<<<128, 256, 0, stream>>>(pa);

    for (int b0 = 0; b0 < B; b0 += BC) {
        const float* imgc = img + (size_t)b0 * HW;
        dim3 cgf(H / 2, BC), cgr(H / 8, BC);

        // merged first layer: k-raw -> R, p-raw -> RpB(=R2 bytes)
        conv1f_k<<<cgf, 256, 0, stream>>>(imgc, polar, wt48,
                                          (const float*)d_in[2], (const float*)d_in[16],
                                          R, RpB, st1 + (size_t)b0 * 16, stp1 + (size_t)b0 * 8);

        // p-tower conv2 (consume RpB before conv2 clobbers R2)
        conv_roll_k<16, 16, 4, 4><<<cgr, 256, 0, stream>>>(
            RpB, stp1 + (size_t)b0 * 8, (const float*)d_in[17], (const float*)d_in[18],
            (const float*)d_in[20], (const short8*)wpkph, (const short8*)wpkpl,
            p2B, stp2 + (size_t)b0 * 8);

        // k-tower conv2, conv3
        conv_roll_k<32, 32, 8, 8><<<cgr, 256, 0, stream>>>(
            R, st1 + (size_t)b0 * 16, (const float*)d_in[3], (const float*)d_in[4],
            (const float*)d_in[6], (const short8*)wpk2h, (const short8*)wpk2l,
            R2, st2 + (size_t)b0 * 16);
        conv_roll_k<32, 16, 8, 4><<<cgr, 256, 0, stream>>>(
            R2, st2 + (size_t)b0 * 16, (const float*)d_in[7], (const float*)d_in[8],
            (const float*)d_in[10], (const short8*)wpk3h, (const short8*)wpk3l,
            h3B, st3 + (size_t)b0 * 8);

        // fused tail
        tail_k<<<dim3(8, BC), 512, 0, stream>>>(
            h3B, p2B, imgc,
            (const float*)d_in[11], (const float*)d_in[12], st3 + (size_t)b0 * 8,
            (const float*)d_in[21], (const float*)d_in[22], stp2 + (size_t)b0 * 8,
            (const float*)d_in[13], (const float*)d_in[14],
            (const float*)d_in[23], (const float*)d_in[24],
            outsrc + (size_t)b0 * HW, outk + (size_t)b0 * HW,
            outpsi + (size_t)b0 * HW, outax + (size_t)b0 * HW,
            outay + (size_t)b0 * HW);
    }
}